// Round 1
// baseline (3774.363 us; speedup 1.0000x reference)
//
#include <hip/hip_runtime.h>
#include <hip/hip_bf16.h>
#include <math.h>

// ---------------------------------------------------------------------------
// BiLSTM-CRF, fp32 end-to-end.
// Sizes: B=64 T=256 CHAR_E=256 POS_E=128 Hp=128 (pos dir), Hm=256 (main dir),
// Dm=640, LBL=20 (START=18, STOP=19).
// Pipeline: gather -> posGEMM -> pos_rec -> mainGEMM -> main_rec -> emit -> viterbi
// ---------------------------------------------------------------------------

#define Bsz 64
#define Tsz 256
#define NROW 16384        // B*T

__device__ __forceinline__ float sigm(float x) { return 1.f / (1.f + expf(-x)); }

// ------------------------- gather: embeddings --------------------------------
__global__ __launch_bounds__(256) void gather_kernel(
    const int* __restrict__ ci, const int* __restrict__ pi, const int* __restrict__ ti,
    const float* __restrict__ ce, const float* __restrict__ pe, const float* __restrict__ te,
    float* __restrict__ tbuf, float* __restrict__ emb) {
  int gid = blockIdx.x * 256 + threadIdx.x;     // NROW*128 threads
  int m = gid >> 7, s = gid & 127;
  if (s < 32) {
    ((float4*)&tbuf[(size_t)m * 128])[s] = ((const float4*)&te[(size_t)ti[m] * 128])[s];
  } else if (s < 96) {
    ((float4*)&emb[(size_t)m * 640])[s - 32] = ((const float4*)&ce[(size_t)ci[m] * 256])[s - 32];
  } else {
    ((float4*)&emb[(size_t)m * 640 + 256])[s - 96] = ((const float4*)&pe[(size_t)pi[m] * 128])[s - 96];
  }
}

// ------------------- fp32 tiled GEMM: C[m,n] = A[m,:].B[n,:] + bias[n] -------
// A [M,K] row-major, B [N,K] row-major (torch weight layout), C row-major ldc.
#define GBM 128
#define GBN 128
#define GBK 16
__global__ __launch_bounds__(256) void gemm_nt(
    const float* __restrict__ A, int lda,
    const float* __restrict__ B, int ldb,
    const float* __restrict__ bias,
    float* __restrict__ C, int ldc, int col0, int K) {
  __shared__ __align__(16) float As[GBK][GBM + 4];
  __shared__ __align__(16) float Bs[GBK][GBN + 4];
  const int tid = threadIdx.x;
  const int tx = tid & 15, ty = tid >> 4;
  const int m0 = blockIdx.y * GBM, n0 = blockIdx.x * GBN;
  float acc[8][8] = {};
  for (int k0 = 0; k0 < K; k0 += GBK) {
#pragma unroll
    for (int r = 0; r < 2; ++r) {
      int fi = tid + r * 256;           // 512 float4 per tile
      int row = fi >> 2, kq = (fi & 3) * 4;
      float4 v = *(const float4*)&A[(size_t)(m0 + row) * lda + k0 + kq];
      As[kq + 0][row] = v.x; As[kq + 1][row] = v.y; As[kq + 2][row] = v.z; As[kq + 3][row] = v.w;
      float4 w = *(const float4*)&B[(size_t)(n0 + row) * ldb + k0 + kq];
      Bs[kq + 0][row] = w.x; Bs[kq + 1][row] = w.y; Bs[kq + 2][row] = w.z; Bs[kq + 3][row] = w.w;
    }
    __syncthreads();
#pragma unroll
    for (int kk = 0; kk < GBK; ++kk) {
      float4 a0 = *(const float4*)&As[kk][ty * 8];
      float4 a1 = *(const float4*)&As[kk][ty * 8 + 4];
      float4 b0 = *(const float4*)&Bs[kk][tx * 8];
      float4 b1 = *(const float4*)&Bs[kk][tx * 8 + 4];
      float av[8] = {a0.x,a0.y,a0.z,a0.w,a1.x,a1.y,a1.z,a1.w};
      float bv[8] = {b0.x,b0.y,b0.z,b0.w,b1.x,b1.y,b1.z,b1.w};
#pragma unroll
      for (int i = 0; i < 8; ++i)
#pragma unroll
        for (int jj = 0; jj < 8; ++jj) acc[i][jj] = fmaf(av[i], bv[jj], acc[i][jj]);
    }
    __syncthreads();
  }
#pragma unroll
  for (int i = 0; i < 8; ++i) {
    size_t m = m0 + ty * 8 + i;
    int nb = n0 + tx * 8;
    float4 o0 = {acc[i][0] + bias[nb+0], acc[i][1] + bias[nb+1], acc[i][2] + bias[nb+2], acc[i][3] + bias[nb+3]};
    float4 o1 = {acc[i][4] + bias[nb+4], acc[i][5] + bias[nb+5], acc[i][6] + bias[nb+6], acc[i][7] + bias[nb+7]};
    *(float4*)&C[m * ldc + col0 + nb]     = o0;
    *(float4*)&C[m * ldc + col0 + nb + 4] = o1;
  }
}

// --------------------------- pos BiLSTM recurrence ---------------------------
// 128 blocks: (b, dir). 512 threads = 512 gate rows. Whh [512][128] fully in VGPRs.
// Gate order i,f,g,o in 128-row groups. Writes emb cols 384 + dir*128 + u.
__global__ __launch_bounds__(512, 2) void pos_rec(
    const int* __restrict__ lengths, const float* __restrict__ gpos,
    const float* __restrict__ Wf, const float* __restrict__ Wb,
    float* __restrict__ emb) {
  const int blk = blockIdx.x;
  const int b = blk >> 1, dir = blk & 1;
  const int j = threadIdx.x;
  const int len = lengths[b];
  const float* W = dir ? Wb : Wf;
  __shared__ __align__(16) float h[128];
  __shared__ float gbuf[512];
  float4 w4[32];
#pragma unroll
  for (int i = 0; i < 32; ++i) w4[i] = *(const float4*)&W[(size_t)j * 128 + i * 4];
  float c = 0.f;
  if (j < 128) h[j] = 0.f;
  __syncthreads();
  for (int t = 0; t < len; ++t) {
    const int idx = dir ? (len - 1 - t) : t;
    float acc = gpos[((size_t)(b * Tsz + idx)) * 1024 + dir * 512 + j];
    const float4* h4 = (const float4*)h;
#pragma unroll
    for (int i = 0; i < 32; ++i) {
      float4 hh = h4[i];
      acc = fmaf(hh.x, w4[i].x, acc); acc = fmaf(hh.y, w4[i].y, acc);
      acc = fmaf(hh.z, w4[i].z, acc); acc = fmaf(hh.w, w4[i].w, acc);
    }
    gbuf[j] = acc;
    __syncthreads();
    if (j < 128) {
      float ig = gbuf[j], fg = gbuf[128 + j], gg = gbuf[256 + j], og = gbuf[384 + j];
      c = sigm(fg) * c + sigm(ig) * tanhf(gg);
      float hn = sigm(og) * tanhf(c);
      h[j] = hn;
      emb[((size_t)(b * Tsz + idx)) * 640 + 384 + dir * 128 + j] = hn;
    }
    __syncthreads();
  }
}

// --------------------------- main BiLSTM recurrence --------------------------
// 256 blocks: (b, dir, half). Block pair (blk, blk^1) covers the 1024 gate rows
// of one (b,dir): half h owns units [half*128, half*128+128). Weights: 208/256
// k-values per row in VGPRs, 48 in LDS. h exchanged between the pair through
// global memory (agent-scope atomics, parity double-buffered) each step.
#define MLDSK 48            // k in [0,48) in LDS -> 12 float4 per row
#define MREGF4 52           // k in [48,256) in regs -> 52 float4
__global__ __launch_bounds__(512, 2) void main_rec(
    const int* __restrict__ lengths, const float* __restrict__ gmain,
    const float* __restrict__ Wf, const float* __restrict__ Wb,
    float* __restrict__ lstm_out, float* __restrict__ hx, unsigned* __restrict__ flags) {
  extern __shared__ float smem[];
  float4* wt4 = (float4*)smem;                       // [12][512] float4
  float* hbuf = smem + (MLDSK / 4) * 512 * 4;        // 256 floats
  float* gbuf = hbuf + 256;                          // 512 floats
  const int blk = blockIdx.x;
  const int b = blk >> 2, dir = (blk >> 1) & 1, half = blk & 1;
  const int j = threadIdx.x;
  const int gc = j >> 7, ul = j & 127;
  const int r = gc * 256 + half * 128 + ul;          // gate row in [0,1024)
  const int len = lengths[b];
  const float* W = dir ? Wb : Wf;                    // [1024][256]
  float4 w4[MREGF4];
#pragma unroll
  for (int i = 0; i < MREGF4; ++i) w4[i] = *(const float4*)&W[(size_t)r * 256 + MLDSK + i * 4];
#pragma unroll
  for (int k4 = 0; k4 < MLDSK / 4; ++k4) wt4[k4 * 512 + j] = *(const float4*)&W[(size_t)r * 256 + k4 * 4];
  float c = 0.f;
  if (j < 256) hbuf[j] = 0.f;
  __syncthreads();
  unsigned* selfF = flags + blk;
  unsigned* partF = flags + (blk ^ 1);
  float* selfB = hx + (size_t)blk * 256;
  float* partB = hx + (size_t)(blk ^ 1) * 256;
  const int obase = dir * 256 + half * 128;
  for (int t = 0; t < len; ++t) {
    const int idx = dir ? (len - 1 - t) : t;
    float acc = gmain[((size_t)(b * Tsz + idx)) * 2048 + dir * 1024 + r];
    const float4* h4 = (const float4*)hbuf;
#pragma unroll
    for (int k4 = 0; k4 < MLDSK / 4; ++k4) {
      float4 hh = h4[k4]; float4 ww = wt4[k4 * 512 + j];
      acc = fmaf(hh.x, ww.x, acc); acc = fmaf(hh.y, ww.y, acc);
      acc = fmaf(hh.z, ww.z, acc); acc = fmaf(hh.w, ww.w, acc);
    }
#pragma unroll
    for (int i = 0; i < MREGF4; ++i) {
      float4 hh = h4[MLDSK / 4 + i];
      acc = fmaf(hh.x, w4[i].x, acc); acc = fmaf(hh.y, w4[i].y, acc);
      acc = fmaf(hh.z, w4[i].z, acc); acc = fmaf(hh.w, w4[i].w, acc);
    }
    gbuf[j] = acc;
    __syncthreads();
    float* selfH = selfB + (t & 1) * 128;
    float* partH = partB + (t & 1) * 128;
    if (j < 128) {
      float ig = gbuf[ul], fg = gbuf[128 + ul], gg = gbuf[256 + ul], og = gbuf[384 + ul];
      c = sigm(fg) * c + sigm(ig) * tanhf(gg);
      float hn = sigm(og) * tanhf(c);
      hbuf[half * 128 + ul] = hn;
      __hip_atomic_store(&selfH[ul], hn, __ATOMIC_RELAXED, __HIP_MEMORY_SCOPE_AGENT);
      lstm_out[((size_t)(b * Tsz + idx)) * 512 + obase + ul] = hn;
    }
    __syncthreads();
    if (j == 0) __hip_atomic_store(selfF, (unsigned)(t + 1), __ATOMIC_RELEASE, __HIP_MEMORY_SCOPE_AGENT);
    if (j == 64) {  // a lane in wave 1 spins; watchdog-capped
      int guard = 0;
      while (__hip_atomic_load(partF, __ATOMIC_ACQUIRE, __HIP_MEMORY_SCOPE_AGENT) < (unsigned)(t + 1)) {
        __builtin_amdgcn_s_sleep(2);
        if (++guard > (1 << 22)) break;
      }
    }
    __syncthreads();
    if (j < 128) hbuf[(half ^ 1) * 128 + j] =
        __hip_atomic_load(&partH[j], __ATOMIC_RELAXED, __HIP_MEMORY_SCOPE_AGENT);
    __syncthreads();
  }
}

// ------------------------------- emit GEMM -----------------------------------
__global__ __launch_bounds__(256) void emit_kernel(
    const float* __restrict__ lstm_out, const float* __restrict__ Wout,
    const float* __restrict__ bout, float* __restrict__ emit) {
  int gid = blockIdx.x * 256 + threadIdx.x;      // NROW*32 threads
  int m = gid >> 5, j = gid & 31;
  if (j >= 20) return;
  const float4* xr = (const float4*)&lstm_out[(size_t)m * 512];
  const float4* wr = (const float4*)&Wout[(size_t)j * 512];
  float acc = bout[j];
#pragma unroll 8
  for (int i = 0; i < 128; ++i) {
    float4 x = xr[i], w = wr[i];
    acc += x.x * w.x + x.y * w.y + x.z * w.z + x.w * w.w;
  }
  emit[(size_t)m * 20 + j] = acc;
}

// ------------------------------- Viterbi -------------------------------------
// One block per batch element. L=20, START=18, STOP=19. jnp.argmax tie-break =
// first max -> strict > keeps lowest index.
__global__ __launch_bounds__(64) void viterbi_kernel(
    const int* __restrict__ lengths, const float* __restrict__ emit,
    const float* __restrict__ trans, int* __restrict__ out) {
  const int b = blockIdx.x, j = threadIdx.x;
  const int len = lengths[b];
  __shared__ float tr[400];
  __shared__ float alpha[20];
  __shared__ float fin[20];
  __shared__ unsigned char bp[256][20];
  for (int i = j; i < 400; i += 64) tr[i] = trans[i];
  __syncthreads();
  if (j < 20) alpha[j] = tr[18 * 20 + j] + emit[(size_t)(b * Tsz) * 20 + j];
  __syncthreads();
  for (int t = 1; t < len; ++t) {
    float best = 0.f; int bi = 0;
    if (j < 20) {
      best = alpha[0] + tr[j];
#pragma unroll
      for (int i = 1; i < 20; ++i) {
        float s = alpha[i] + tr[i * 20 + j];
        if (s > best) { best = s; bi = i; }
      }
      best += emit[((size_t)(b * Tsz + t)) * 20 + j];
    }
    __syncthreads();
    if (j < 20) { alpha[j] = best; bp[t][j] = (unsigned char)bi; }
    __syncthreads();
  }
  if (j < 20) fin[j] = alpha[j] + tr[j * 20 + 19];
  __syncthreads();
  if (j == 0) {
    float best = fin[0]; int tag = 0;
    for (int i = 1; i < 20; ++i) if (fin[i] > best) { best = fin[i]; tag = i; }
    out[b * Tsz + len - 1] = tag;
    for (int t = len - 1; t >= 1; --t) { tag = bp[t][tag]; out[b * Tsz + t - 1] = tag; }
  }
  for (int t = len + j; t < Tsz; t += 64) out[b * Tsz + t] = 0;
}

// ------------------------------- launcher ------------------------------------
extern "C" void kernel_launch(void* const* d_in, const int* in_sizes, int n_in,
                              void* d_out, int out_size, void* d_ws, size_t ws_size,
                              hipStream_t stream) {
  const int*   char_in = (const int*)d_in[0];
  const int*   pos_in  = (const int*)d_in[1];
  const int*   tag_in  = (const int*)d_in[2];
  const int*   lengths = (const int*)d_in[3];
  // d_in[4] = mask: recomputed from lengths, unused.
  const float* ce      = (const float*)d_in[5];
  const float* pe      = (const float*)d_in[6];
  const float* te      = (const float*)d_in[7];
  const float* pWih_f  = (const float*)d_in[8];
  const float* pWhh_f  = (const float*)d_in[9];
  const float* pb_f    = (const float*)d_in[10];
  const float* pWih_b  = (const float*)d_in[11];
  const float* pWhh_b  = (const float*)d_in[12];
  const float* pb_b    = (const float*)d_in[13];
  const float* mWih_f  = (const float*)d_in[14];
  const float* mWhh_f  = (const float*)d_in[15];
  const float* mb_f    = (const float*)d_in[16];
  const float* mWih_b  = (const float*)d_in[17];
  const float* mWhh_b  = (const float*)d_in[18];
  const float* mb_b    = (const float*)d_in[19];
  const float* W_out   = (const float*)d_in[20];
  const float* b_out   = (const float*)d_in[21];
  const float* trans   = (const float*)d_in[22];

  float* ws = (float*)d_ws;
  // ws layout (float offsets). GMAIN reuses TBUF/GPOS region (dead by then).
  const size_t EMB     = 0;                          // 16384*640
  const size_t LSTMOUT = EMB + (size_t)NROW * 640;   // 16384*512
  const size_t EMIT    = LSTMOUT + (size_t)NROW * 512;
  const size_t HX      = EMIT + (size_t)NROW * 20;   // 256 blocks * 256
  const size_t FLAGS   = HX + 256 * 256;             // 256 uints
  const size_t TBUF    = FLAGS + 256;                // 16384*128
  const size_t GPOS    = TBUF + (size_t)NROW * 128;  // 16384*1024
  const size_t GMAIN   = TBUF;                       // 16384*2048 (overlaps TBUF+GPOS)

  hipMemsetAsync(ws + FLAGS, 0, 256 * sizeof(unsigned), stream);

  gather_kernel<<<8192, 256, 0, stream>>>(char_in, pos_in, tag_in, ce, pe, te,
                                          ws + TBUF, ws + EMB);

  // pos input GEMMs: [16384,128] @ [512,128]^T  (+bias), out stride 1024
  gemm_nt<<<dim3(4, 128), 256, 0, stream>>>(ws + TBUF, 128, pWih_f, 128, pb_f,
                                            ws + GPOS, 1024, 0, 128);
  gemm_nt<<<dim3(4, 128), 256, 0, stream>>>(ws + TBUF, 128, pWih_b, 128, pb_b,
                                            ws + GPOS, 1024, 512, 128);

  pos_rec<<<128, 512, 0, stream>>>(lengths, ws + GPOS, pWhh_f, pWhh_b, ws + EMB);

  // main input GEMMs: [16384,640] @ [1024,640]^T (+bias), out stride 2048
  gemm_nt<<<dim3(8, 128), 256, 0, stream>>>(ws + EMB, 640, mWih_f, 640, mb_f,
                                            ws + GMAIN, 2048, 0, 640);
  gemm_nt<<<dim3(8, 128), 256, 0, stream>>>(ws + EMB, 640, mWih_b, 640, mb_b,
                                            ws + GMAIN, 2048, 1024, 640);

  const int SMEM = (MLDSK / 4) * 512 * 16 + 256 * 4 + 512 * 4;  // 101376 B
  hipFuncSetAttribute((const void*)main_rec,
                      hipFuncAttributeMaxDynamicSharedMemorySize, SMEM);
  main_rec<<<256, 512, SMEM, stream>>>(lengths, ws + GMAIN, mWhh_f, mWhh_b,
                                       ws + LSTMOUT, ws + HX, (unsigned*)(ws + FLAGS));

  emit_kernel<<<2048, 256, 0, stream>>>(ws + LSTMOUT, W_out, b_out, ws + EMIT);

  viterbi_kernel<<<64, 64, 0, stream>>>(lengths, ws + EMIT, trans, (int*)d_out);
}

// Round 2
// 2256.692 us; speedup vs baseline: 1.6725x; 1.6725x over previous
//
#include <hip/hip_runtime.h>
#include <hip/hip_bf16.h>
#include <math.h>

// ---------------------------------------------------------------------------
// BiLSTM-CRF, fp32 end-to-end.
// Sizes: B=64 T=256 CHAR_E=256 POS_E=128 Hp=128 (pos dir), Hm=256 (main dir),
// Dm=640, LBL=20 (START=18, STOP=19).
// Pipeline: gather -> posGEMM -> pos_rec -> mainGEMM -> main_rec -> emit -> viterbi
// R2: main_rec cross-block h-exchange made fence-free: packed (tag|h) 64-bit
// relaxed agent atomics replace release/acquire (which caused per-step L2
// writeback+invalidate -> 10.5us/step). 2 barriers/step, gmain prefetch.
// ---------------------------------------------------------------------------

#define Bsz 64
#define Tsz 256
#define NROW 16384        // B*T

__device__ __forceinline__ float sigm(float x) { return 1.f / (1.f + expf(-x)); }

// ------------------------- gather: embeddings --------------------------------
__global__ __launch_bounds__(256) void gather_kernel(
    const int* __restrict__ ci, const int* __restrict__ pi, const int* __restrict__ ti,
    const float* __restrict__ ce, const float* __restrict__ pe, const float* __restrict__ te,
    float* __restrict__ tbuf, float* __restrict__ emb) {
  int gid = blockIdx.x * 256 + threadIdx.x;     // NROW*128 threads
  int m = gid >> 7, s = gid & 127;
  if (s < 32) {
    ((float4*)&tbuf[(size_t)m * 128])[s] = ((const float4*)&te[(size_t)ti[m] * 128])[s];
  } else if (s < 96) {
    ((float4*)&emb[(size_t)m * 640])[s - 32] = ((const float4*)&ce[(size_t)ci[m] * 256])[s - 32];
  } else {
    ((float4*)&emb[(size_t)m * 640 + 256])[s - 96] = ((const float4*)&pe[(size_t)pi[m] * 128])[s - 96];
  }
}

// ------------------- fp32 tiled GEMM: C[m,n] = A[m,:].B[n,:] + bias[n] -------
// A [M,K] row-major, B [N,K] row-major (torch weight layout), C row-major ldc.
#define GBM 128
#define GBN 128
#define GBK 16
__global__ __launch_bounds__(256) void gemm_nt(
    const float* __restrict__ A, int lda,
    const float* __restrict__ B, int ldb,
    const float* __restrict__ bias,
    float* __restrict__ C, int ldc, int col0, int K) {
  __shared__ __align__(16) float As[GBK][GBM + 4];
  __shared__ __align__(16) float Bs[GBK][GBN + 4];
  const int tid = threadIdx.x;
  const int tx = tid & 15, ty = tid >> 4;
  const int m0 = blockIdx.y * GBM, n0 = blockIdx.x * GBN;
  float acc[8][8] = {};
  for (int k0 = 0; k0 < K; k0 += GBK) {
#pragma unroll
    for (int r = 0; r < 2; ++r) {
      int fi = tid + r * 256;           // 512 float4 per tile
      int row = fi >> 2, kq = (fi & 3) * 4;
      float4 v = *(const float4*)&A[(size_t)(m0 + row) * lda + k0 + kq];
      As[kq + 0][row] = v.x; As[kq + 1][row] = v.y; As[kq + 2][row] = v.z; As[kq + 3][row] = v.w;
      float4 w = *(const float4*)&B[(size_t)(n0 + row) * ldb + k0 + kq];
      Bs[kq + 0][row] = w.x; Bs[kq + 1][row] = w.y; Bs[kq + 2][row] = w.z; Bs[kq + 3][row] = w.w;
    }
    __syncthreads();
#pragma unroll
    for (int kk = 0; kk < GBK; ++kk) {
      float4 a0 = *(const float4*)&As[kk][ty * 8];
      float4 a1 = *(const float4*)&As[kk][ty * 8 + 4];
      float4 b0 = *(const float4*)&Bs[kk][tx * 8];
      float4 b1 = *(const float4*)&Bs[kk][tx * 8 + 4];
      float av[8] = {a0.x,a0.y,a0.z,a0.w,a1.x,a1.y,a1.z,a1.w};
      float bv[8] = {b0.x,b0.y,b0.z,b0.w,b1.x,b1.y,b1.z,b1.w};
#pragma unroll
      for (int i = 0; i < 8; ++i)
#pragma unroll
        for (int jj = 0; jj < 8; ++jj) acc[i][jj] = fmaf(av[i], bv[jj], acc[i][jj]);
    }
    __syncthreads();
  }
#pragma unroll
  for (int i = 0; i < 8; ++i) {
    size_t m = m0 + ty * 8 + i;
    int nb = n0 + tx * 8;
    float4 o0 = {acc[i][0] + bias[nb+0], acc[i][1] + bias[nb+1], acc[i][2] + bias[nb+2], acc[i][3] + bias[nb+3]};
    float4 o1 = {acc[i][4] + bias[nb+4], acc[i][5] + bias[nb+5], acc[i][6] + bias[nb+6], acc[i][7] + bias[nb+7]};
    *(float4*)&C[m * ldc + col0 + nb]     = o0;
    *(float4*)&C[m * ldc + col0 + nb + 4] = o1;
  }
}

// --------------------------- pos BiLSTM recurrence ---------------------------
// 128 blocks: (b, dir). 512 threads = 512 gate rows. Whh [512][128] fully in VGPRs.
// Gate order i,f,g,o in 128-row groups. Writes emb cols 384 + dir*128 + u.
__global__ __launch_bounds__(512, 2) void pos_rec(
    const int* __restrict__ lengths, const float* __restrict__ gpos,
    const float* __restrict__ Wf, const float* __restrict__ Wb,
    float* __restrict__ emb) {
  const int blk = blockIdx.x;
  const int b = blk >> 1, dir = blk & 1;
  const int j = threadIdx.x;
  const int len = lengths[b];
  const float* W = dir ? Wb : Wf;
  __shared__ __align__(16) float h[128];
  __shared__ float gbuf[512];
  float4 w4[32];
#pragma unroll
  for (int i = 0; i < 32; ++i) w4[i] = *(const float4*)&W[(size_t)j * 128 + i * 4];
  float c = 0.f;
  if (j < 128) h[j] = 0.f;
  __syncthreads();
  for (int t = 0; t < len; ++t) {
    const int idx = dir ? (len - 1 - t) : t;
    float acc = gpos[((size_t)(b * Tsz + idx)) * 1024 + dir * 512 + j];
    const float4* h4 = (const float4*)h;
#pragma unroll
    for (int i = 0; i < 32; ++i) {
      float4 hh = h4[i];
      acc = fmaf(hh.x, w4[i].x, acc); acc = fmaf(hh.y, w4[i].y, acc);
      acc = fmaf(hh.z, w4[i].z, acc); acc = fmaf(hh.w, w4[i].w, acc);
    }
    gbuf[j] = acc;
    __syncthreads();
    if (j < 128) {
      float ig = gbuf[j], fg = gbuf[128 + j], gg = gbuf[256 + j], og = gbuf[384 + j];
      c = sigm(fg) * c + sigm(ig) * tanhf(gg);
      float hn = sigm(og) * tanhf(c);
      h[j] = hn;
      emb[((size_t)(b * Tsz + idx)) * 640 + 384 + dir * 128 + j] = hn;
    }
    __syncthreads();
  }
}

// --------------------------- main BiLSTM recurrence --------------------------
// 256 blocks: (b, dir, half). Block pair (blk, blk^1) covers the 1024 gate rows
// of one (b,dir): half h owns units [half*128, half*128+128). Weights: 208/256
// k-values per row in VGPRs, 48 in LDS. h exchanged between the pair through
// global memory: packed (step_tag<<32 | h_bits) 8-byte RELAXED agent atomics
// (no release/acquire -> no L2 writeback/invalidate). Parity double-buffer.
#define MLDSK 48            // k in [0,48) in LDS -> 12 float4 per row
#define MREGF4 52           // k in [48,256) in regs -> 52 float4
__global__ __launch_bounds__(512, 1) void main_rec(
    const int* __restrict__ lengths, const float* __restrict__ gmain,
    const float* __restrict__ Wf, const float* __restrict__ Wb,
    float* __restrict__ lstm_out, unsigned long long* __restrict__ hx) {
  extern __shared__ float smem[];
  float4* wt4 = (float4*)smem;                       // [12][512] float4
  float* hbuf = smem + (MLDSK / 4) * 512 * 4;        // 256 floats
  float* gbuf = hbuf + 256;                          // 512 floats
  const int blk = blockIdx.x;
  const int b = blk >> 2, dir = (blk >> 1) & 1, half = blk & 1;
  const int j = threadIdx.x;
  const int gc = j >> 7, ul = j & 127;
  const int r = gc * 256 + half * 128 + ul;          // gate row in [0,1024)
  const int len = lengths[b];
  const float* W = dir ? Wb : Wf;                    // [1024][256]
  float4 w4[MREGF4];
#pragma unroll
  for (int i = 0; i < MREGF4; ++i) w4[i] = *(const float4*)&W[(size_t)r * 256 + MLDSK + i * 4];
#pragma unroll
  for (int k4 = 0; k4 < MLDSK / 4; ++k4) wt4[k4 * 512 + j] = *(const float4*)&W[(size_t)r * 256 + k4 * 4];
  float c = 0.f;
  if (j < 256) hbuf[j] = 0.f;
  __syncthreads();
  unsigned long long* selfB = hx + (size_t)blk * 256;
  unsigned long long* partB = hx + (size_t)(blk ^ 1) * 256;
  const int obase = dir * 256 + half * 128;
  // prefetch t=0 gate row
  int idx0 = dir ? (len - 1) : 0;
  float gcur = gmain[((size_t)(b * Tsz + idx0)) * 2048 + dir * 1024 + r];
  for (int t = 0; t < len; ++t) {
    const int idx = dir ? (len - 1 - t) : t;
    // issue next step's gate-row load early (hidden under matvec+exchange)
    const int tn = (t + 1 < len) ? t + 1 : t;
    const int idxn = dir ? (len - 1 - tn) : tn;
    float gnext = gmain[((size_t)(b * Tsz + idxn)) * 2048 + dir * 1024 + r];
    float acc = gcur;
    const float4* h4 = (const float4*)hbuf;
#pragma unroll
    for (int k4 = 0; k4 < MLDSK / 4; ++k4) {
      float4 hh = h4[k4]; float4 ww = wt4[k4 * 512 + j];
      acc = fmaf(hh.x, ww.x, acc); acc = fmaf(hh.y, ww.y, acc);
      acc = fmaf(hh.z, ww.z, acc); acc = fmaf(hh.w, ww.w, acc);
    }
#pragma unroll
    for (int i = 0; i < MREGF4; ++i) {
      float4 hh = h4[MLDSK / 4 + i];
      acc = fmaf(hh.x, w4[i].x, acc); acc = fmaf(hh.y, w4[i].y, acc);
      acc = fmaf(hh.z, w4[i].z, acc); acc = fmaf(hh.w, w4[i].w, acc);
    }
    gbuf[j] = acc;
    __syncthreads();
    if (j < 128) {
      float ig = gbuf[ul], fg = gbuf[128 + ul], gg = gbuf[256 + ul], og = gbuf[384 + ul];
      c = sigm(fg) * c + sigm(ig) * tanhf(gg);
      float hn = sigm(og) * tanhf(c);
      lstm_out[((size_t)(b * Tsz + idx)) * 512 + obase + ul] = hn;
      union { float f; unsigned u; } cv; cv.f = hn;
      unsigned long long pk = ((unsigned long long)(unsigned)(t + 1) << 32) | (unsigned long long)cv.u;
      __hip_atomic_store(&selfB[(t & 1) * 128 + ul], pk, __ATOMIC_RELAXED, __HIP_MEMORY_SCOPE_AGENT);
      unsigned long long pv;
      int guard = 0;
      for (;;) {
        pv = __hip_atomic_load(&partB[(t & 1) * 128 + ul], __ATOMIC_RELAXED, __HIP_MEMORY_SCOPE_AGENT);
        if ((unsigned)(pv >> 32) == (unsigned)(t + 1)) break;
        if (++guard > (1 << 22)) break;   // watchdog
        __builtin_amdgcn_s_sleep(1);
      }
      union { unsigned u; float f; } hv; hv.u = (unsigned)pv;
      hbuf[half * 128 + ul] = hn;
      hbuf[(half ^ 1) * 128 + ul] = hv.f;
    }
    __syncthreads();
    gcur = gnext;
  }
}

// ------------------------------- emit GEMM -----------------------------------
__global__ __launch_bounds__(256) void emit_kernel(
    const float* __restrict__ lstm_out, const float* __restrict__ Wout,
    const float* __restrict__ bout, float* __restrict__ emit) {
  int gid = blockIdx.x * 256 + threadIdx.x;      // NROW*32 threads
  int m = gid >> 5, j = gid & 31;
  if (j >= 20) return;
  const float4* xr = (const float4*)&lstm_out[(size_t)m * 512];
  const float4* wr = (const float4*)&Wout[(size_t)j * 512];
  float acc = bout[j];
#pragma unroll 8
  for (int i = 0; i < 128; ++i) {
    float4 x = xr[i], w = wr[i];
    acc += x.x * w.x + x.y * w.y + x.z * w.z + x.w * w.w;
  }
  emit[(size_t)m * 20 + j] = acc;
}

// ------------------------------- Viterbi -------------------------------------
// One block per batch element. L=20, START=18, STOP=19. jnp.argmax tie-break =
// first max -> strict > keeps lowest index.
__global__ __launch_bounds__(64) void viterbi_kernel(
    const int* __restrict__ lengths, const float* __restrict__ emit,
    const float* __restrict__ trans, int* __restrict__ out) {
  const int b = blockIdx.x, j = threadIdx.x;
  const int len = lengths[b];
  __shared__ float tr[400];
  __shared__ float alpha[20];
  __shared__ float fin[20];
  __shared__ unsigned char bp[256][20];
  for (int i = j; i < 400; i += 64) tr[i] = trans[i];
  __syncthreads();
  if (j < 20) alpha[j] = tr[18 * 20 + j] + emit[(size_t)(b * Tsz) * 20 + j];
  __syncthreads();
  for (int t = 1; t < len; ++t) {
    float best = 0.f; int bi = 0;
    if (j < 20) {
      best = alpha[0] + tr[j];
#pragma unroll
      for (int i = 1; i < 20; ++i) {
        float s = alpha[i] + tr[i * 20 + j];
        if (s > best) { best = s; bi = i; }
      }
      best += emit[((size_t)(b * Tsz + t)) * 20 + j];
    }
    __syncthreads();
    if (j < 20) { alpha[j] = best; bp[t][j] = (unsigned char)bi; }
    __syncthreads();
  }
  if (j < 20) fin[j] = alpha[j] + tr[j * 20 + 19];
  __syncthreads();
  if (j == 0) {
    float best = fin[0]; int tag = 0;
    for (int i = 1; i < 20; ++i) if (fin[i] > best) { best = fin[i]; tag = i; }
    out[b * Tsz + len - 1] = tag;
    for (int t = len - 1; t >= 1; --t) { tag = bp[t][tag]; out[b * Tsz + t - 1] = tag; }
  }
  for (int t = len + j; t < Tsz; t += 64) out[b * Tsz + t] = 0;
}

// ------------------------------- launcher ------------------------------------
extern "C" void kernel_launch(void* const* d_in, const int* in_sizes, int n_in,
                              void* d_out, int out_size, void* d_ws, size_t ws_size,
                              hipStream_t stream) {
  const int*   char_in = (const int*)d_in[0];
  const int*   pos_in  = (const int*)d_in[1];
  const int*   tag_in  = (const int*)d_in[2];
  const int*   lengths = (const int*)d_in[3];
  // d_in[4] = mask: recomputed from lengths, unused.
  const float* ce      = (const float*)d_in[5];
  const float* pe      = (const float*)d_in[6];
  const float* te      = (const float*)d_in[7];
  const float* pWih_f  = (const float*)d_in[8];
  const float* pWhh_f  = (const float*)d_in[9];
  const float* pb_f    = (const float*)d_in[10];
  const float* pWih_b  = (const float*)d_in[11];
  const float* pWhh_b  = (const float*)d_in[12];
  const float* pb_b    = (const float*)d_in[13];
  const float* mWih_f  = (const float*)d_in[14];
  const float* mWhh_f  = (const float*)d_in[15];
  const float* mb_f    = (const float*)d_in[16];
  const float* mWih_b  = (const float*)d_in[17];
  const float* mWhh_b  = (const float*)d_in[18];
  const float* mb_b    = (const float*)d_in[19];
  const float* W_out   = (const float*)d_in[20];
  const float* b_out   = (const float*)d_in[21];
  const float* trans   = (const float*)d_in[22];

  float* ws = (float*)d_ws;
  // ws layout (float offsets). GMAIN reuses TBUF/GPOS region (dead by then).
  const size_t EMB     = 0;                          // 16384*640
  const size_t LSTMOUT = EMB + (size_t)NROW * 640;   // 16384*512
  const size_t EMIT    = LSTMOUT + (size_t)NROW * 512;
  const size_t HX      = EMIT + (size_t)NROW * 20;   // 256 blocks * 256 ull (8B-aligned: even)
  const size_t TBUF    = HX + 256 * 256 * 2;         // 16384*128
  const size_t GPOS    = TBUF + (size_t)NROW * 128;  // 16384*1024
  const size_t GMAIN   = TBUF;                       // 16384*2048 (overlaps TBUF+GPOS+)

  // clear h-exchange tags (stale tags from a previous replay must not match)
  hipMemsetAsync(ws + HX, 0, 256 * 256 * sizeof(unsigned long long), stream);

  gather_kernel<<<8192, 256, 0, stream>>>(char_in, pos_in, tag_in, ce, pe, te,
                                          ws + TBUF, ws + EMB);

  // pos input GEMMs: [16384,128] @ [512,128]^T  (+bias), out stride 1024
  gemm_nt<<<dim3(4, 128), 256, 0, stream>>>(ws + TBUF, 128, pWih_f, 128, pb_f,
                                            ws + GPOS, 1024, 0, 128);
  gemm_nt<<<dim3(4, 128), 256, 0, stream>>>(ws + TBUF, 128, pWih_b, 128, pb_b,
                                            ws + GPOS, 1024, 512, 128);

  pos_rec<<<128, 512, 0, stream>>>(lengths, ws + GPOS, pWhh_f, pWhh_b, ws + EMB);

  // main input GEMMs: [16384,640] @ [1024,640]^T (+bias), out stride 2048
  gemm_nt<<<dim3(8, 128), 256, 0, stream>>>(ws + EMB, 640, mWih_f, 640, mb_f,
                                            ws + GMAIN, 2048, 0, 640);
  gemm_nt<<<dim3(8, 128), 256, 0, stream>>>(ws + EMB, 640, mWih_b, 640, mb_b,
                                            ws + GMAIN, 2048, 1024, 640);

  const int SMEM = (MLDSK / 4) * 512 * 16 + 256 * 4 + 512 * 4;  // 101376 B
  hipFuncSetAttribute((const void*)main_rec,
                      hipFuncAttributeMaxDynamicSharedMemorySize, SMEM);
  main_rec<<<256, 512, SMEM, stream>>>(lengths, ws + GMAIN, mWhh_f, mWhh_b,
                                       ws + LSTMOUT, (unsigned long long*)(ws + HX));

  emit_kernel<<<2048, 256, 0, stream>>>(ws + LSTMOUT, W_out, b_out, ws + EMIT);

  viterbi_kernel<<<64, 64, 0, stream>>>(lengths, ws + EMIT, trans, (int*)d_out);
}